// Round 2
// baseline (3442.027 us; speedup 1.0000x reference)
//
#include <hip/hip_runtime.h>
#include <hip/hip_cooperative_groups.h>

namespace cg = cooperative_groups;

static constexpr int BN    = 512;    // batch
static constexpr int ID    = 1024;   // input dim
static constexpr int HDm   = 2048;   // hidden dim
static constexpr int LD    = 1000;   // labels
static constexpr int TMAXc = 32;
static constexpr float ALPHAc = 0.05f;

// ---------------------------------------------------------------------------
// Generic 64 x (16*TNW) fp32 tile GEMM, BK=16, 256 threads, 4xTNW microtile.
// A[M,K] row-major, B[K,N] row-major (optionally multiplied elementwise by B2).
// ---------------------------------------------------------------------------
template<int TNW, bool MASK>
__device__ __forceinline__ void gemm_tile(
    const float* __restrict__ A, int lda,
    const float* __restrict__ Bm, const float* __restrict__ B2, int ldb,
    int K, int Ncols, int row0, int col0,
    float (&acc)[4][TNW], float* __restrict__ As, float* __restrict__ Bs)
{
    constexpr int TN = 16 * TNW;
    const int tid = threadIdx.x;
    const int tx = tid & 15, ty = tid >> 4;
#pragma unroll
    for (int i = 0; i < 4; ++i)
#pragma unroll
        for (int j = 0; j < TNW; ++j) acc[i][j] = 0.f;

    const int arow = tid >> 2;          // 0..63
    const int ak4  = (tid & 3) << 2;    // 0,4,8,12
    const int bk   = tid >> 4;          // 0..15
    const int bn   = (tid & 15) * TNW;  // col within tile
    const float* Ap  = A + (size_t)(row0 + arow) * lda + ak4;
    const float* Bp  = Bm + (size_t)bk * ldb + col0 + bn;
    const float* B2p = MASK ? (B2 + (size_t)bk * ldb + col0 + bn) : nullptr;
    const bool bok = (col0 + bn) < Ncols;   // vector lies fully in-bounds (N % TNW == 0)

    for (int k0 = 0; k0 < K; k0 += 16) {
        float4 av = *(const float4*)(Ap + k0);
        float bv[TNW];
#pragma unroll
        for (int j = 0; j < TNW; ++j) bv[j] = 0.f;
        if (bok) {
#pragma unroll
            for (int j = 0; j < TNW; ++j) bv[j] = Bp[(size_t)k0 * ldb + j];
            if (MASK) {
#pragma unroll
                for (int j = 0; j < TNW; ++j) bv[j] *= B2p[(size_t)k0 * ldb + j];
            }
        }
        __syncthreads();   // previous iteration's LDS reads complete
        As[(ak4 + 0) * 68 + arow] = av.x;   // A staged transposed [k][m], pad 68
        As[(ak4 + 1) * 68 + arow] = av.y;
        As[(ak4 + 2) * 68 + arow] = av.z;
        As[(ak4 + 3) * 68 + arow] = av.w;
#pragma unroll
        for (int j = 0; j < TNW; ++j) Bs[bk * TN + bn + j] = bv[j];
        __syncthreads();
#pragma unroll
        for (int k = 0; k < 16; ++k) {
            float4 a4 = *(const float4*)(As + k * 68 + ty * 4);
            float b[TNW];
#pragma unroll
            for (int j = 0; j < TNW; ++j) b[j] = Bs[k * TN + tx * TNW + j];
            const float a[4] = {a4.x, a4.y, a4.z, a4.w};
#pragma unroll
            for (int i = 0; i < 4; ++i)
#pragma unroll
                for (int j = 0; j < TNW; ++j) acc[i][j] = fmaf(a[i], b[j], acc[i][j]);
        }
    }
}

// ---------------------------------------------------------------------------
// Prep kernels
// ---------------------------------------------------------------------------
__global__ void k_init(int* active, int* nact, float* scal)
{
    int i = blockIdx.x * blockDim.x + threadIdx.x;
    if (i < BN) active[i] = 1;
    if (i < TMAXc + 1) nact[i] = 0;
    if (i < 8) scal[i] = 0.f;
}

// max column L1 norm of RH*MH -> atomicMax into scal[0]
__global__ __launch_bounds__(256) void k_colsum_wh(const float* __restrict__ RH,
                                                   const float* __restrict__ MH,
                                                   float* scal)
{
    const int col = blockIdx.x * 64 + (threadIdx.x & 63);
    const int rs  = threadIdx.x >> 6;   // 0..3
    float s = 0.f;
    for (int i = rs; i < HDm; i += 4)
        s += fabsf(RH[(size_t)i * HDm + col] * MH[(size_t)i * HDm + col]);
    __shared__ float red[4][64];
    red[rs][threadIdx.x & 63] = s;
    __syncthreads();
    if (threadIdx.x < 64) {
        float c = red[0][threadIdx.x] + red[1][threadIdx.x] +
                  red[2][threadIdx.x] + red[3][threadIdx.x];
#pragma unroll
        for (int off = 1; off < 64; off <<= 1) c = fmaxf(c, __shfl_xor(c, off));
        if (threadIdx.x == 0)
            atomicMax((unsigned int*)&scal[0], __float_as_uint(c));
    }
}

// W_HL = RHL*MHL (stored), whl_inf = max col L1 -> atomicMax into scal[1]
__global__ __launch_bounds__(256) void k_colsum_whl(const float* __restrict__ RHL,
                                                    const float* __restrict__ MHL,
                                                    float* __restrict__ W_HL,
                                                    float* scal)
{
    const int col = blockIdx.x * 64 + (threadIdx.x & 63);
    const int rs  = threadIdx.x >> 6;
    const bool ok = col < LD;
    float s = 0.f;
    if (ok) {
        for (int i = rs; i < HDm; i += 4) {
            float w = RHL[(size_t)i * LD + col] * MHL[(size_t)i * LD + col];
            W_HL[(size_t)i * LD + col] = w;
            s += fabsf(w);
        }
    }
    __shared__ float red[4][64];
    red[rs][threadIdx.x & 63] = s;
    __syncthreads();
    if (threadIdx.x < 64) {
        float c = red[0][threadIdx.x] + red[1][threadIdx.x] +
                  red[2][threadIdx.x] + red[3][threadIdx.x];
#pragma unroll
        for (int off = 1; off < 64; off <<= 1) c = fmaxf(c, __shfl_xor(c, off));
        if (threadIdx.x == 0)
            atomicMax((unsigned int*)&scal[1], __float_as_uint(c));
    }
}

__global__ void k_scalars(float* scal)
{
    if (threadIdx.x == 0 && blockIdx.x == 0) {
        scal[2] = 0.95f / fmaxf(scal[0], 1e-8f);       // scale
        scal[3] = scal[1] * (0.95f / 0.05f);           // gamma_coef = whl_inf * rho/(1-rho)
    }
}

__global__ void k_wh(const float* __restrict__ RH, const float* __restrict__ MH,
                     const float* __restrict__ scal, float* __restrict__ W_H)
{
    const float s = scal[2];
    size_t i = (size_t)blockIdx.x * blockDim.x + threadIdx.x;   // float4 index
    if (i < (size_t)HDm * HDm / 4) {
        float4 r = ((const float4*)RH)[i];
        float4 m = ((const float4*)MH)[i];
        float4 w = make_float4(r.x * m.x * s, r.y * m.y * s, r.z * m.z * s, r.w * m.w * s);
        ((float4*)W_H)[i] = w;
    }
}

// drive = x @ (RIH*MIH) + BH
__global__ __launch_bounds__(256) void k_drive(const float* __restrict__ x,
                                               const float* __restrict__ RIH,
                                               const float* __restrict__ MIH,
                                               const float* __restrict__ BH,
                                               float* __restrict__ drive)
{
    __shared__ float lds[16 * 68 + 16 * 64];
    float* As = lds;
    float* Bs = lds + 16 * 68;
    const int ntiles = (BN / 64) * (HDm / 64);   // 256
    for (int tile = blockIdx.x; tile < ntiles; tile += gridDim.x) {
        const int row0 = (tile >> 5) * 64;
        const int col0 = (tile & 31) * 64;
        float acc[4][4];
        gemm_tile<4, true>(x, ID, RIH, MIH, HDm, ID, HDm, row0, col0, acc, As, Bs);
        const int tx = threadIdx.x & 15, ty = threadIdx.x >> 4;
#pragma unroll
        for (int i = 0; i < 4; ++i) {
            const int r = row0 + ty * 4 + i;
#pragma unroll
            for (int j = 0; j < 4; ++j) {
                const int c = col0 + tx * 4 + j;
                drive[(size_t)r * HDm + c] = acc[i][j] + BH[c];
            }
        }
    }
}

// ---------------------------------------------------------------------------
// Cooperative loop kernel: the whole 32-step iteration with early exit.
// ---------------------------------------------------------------------------
__global__ __launch_bounds__(256) void k_crp_loop(
    const float* __restrict__ W_H, const float* __restrict__ W_HL,
    const float* __restrict__ drive, const float* __restrict__ BL,
    float* Ha, float* Hb, float* logits,
    int* active, int* nact, const float* scal, float* out)
{
    cg::grid_group grid = cg::this_grid();
    __shared__ float lds[16 * 68 + 16 * 64];
    float* As = lds;
    float* Bs = lds + 16 * 68;
    const int nb = gridDim.x, bid = blockIdx.x, tid = threadIdx.x;
    const int tx = tid & 15, ty = tid >> 4;
    const float gamma2 = 2.f * scal[3];
    float* Hs = Ha;
    float* Hn = Hb;

    for (int t = 1; t <= TMAXc; ++t) {
        // ---- P1: Hn = select(active, LeakyReLU(Hs @ W_H + drive), Hs) ----
        const int nt1 = (BN / 64) * (HDm / 64);   // 256
        for (int tile = bid; tile < nt1; tile += nb) {
            const int row0 = (tile >> 5) * 64;
            const int col0 = (tile & 31) * 64;
            float acc[4][4];
            gemm_tile<4, false>(Hs, HDm, W_H, nullptr, HDm, HDm, HDm, row0, col0, acc, As, Bs);
#pragma unroll
            for (int i = 0; i < 4; ++i) {
                const int r = row0 + ty * 4 + i;
                const int act_r = ((volatile const int*)active)[r];
#pragma unroll
                for (int j = 0; j < 4; ++j) {
                    const int c = col0 + tx * 4 + j;
                    float pre = acc[i][j] + drive[(size_t)r * HDm + c];
                    float a = pre >= 0.f ? pre : ALPHAc * pre;
                    Hn[(size_t)r * HDm + c] = act_r ? a : Hs[(size_t)r * HDm + c];
                }
            }
        }
        grid.sync();

        // ---- P2: logits = Hn @ W_HL + BL ----
        const int nt2 = (BN / 64) * 32;   // col tiles of 32 (last partially OOB) = 256
        for (int tile = bid; tile < nt2; tile += nb) {
            const int row0 = (tile >> 5) * 64;
            const int col0 = (tile & 31) * 32;
            float acc[4][2];
            gemm_tile<2, false>(Hn, HDm, W_HL, nullptr, LD, HDm, LD, row0, col0, acc, As, Bs);
#pragma unroll
            for (int i = 0; i < 4; ++i) {
                const int r = row0 + ty * 4 + i;
#pragma unroll
                for (int j = 0; j < 2; ++j) {
                    const int c = col0 + tx * 2 + j;
                    if (c < LD) logits[(size_t)r * LD + c] = acc[i][j] + BL[c];
                }
            }
        }
        grid.sync();

        // ---- P3: per-row certification (wave per row) ----
        const int lane = tid & 63;
        const int wave = (bid * 256 + tid) >> 6;
        const int nwaves = nb * 4;
        for (int b = wave; b < BN; b += nwaves) {
            if (!((volatile const int*)active)[b]) continue;
            const float* hn = Hn + (size_t)b * HDm;
            const float* hs = Hs + (size_t)b * HDm;
            float dh = 0.f;
            for (int h = lane; h < HDm; h += 64)
                dh = fmaxf(dh, fabsf(hn[h] - hs[h]));
#pragma unroll
            for (int off = 1; off < 64; off <<= 1)
                dh = fmaxf(dh, __shfl_xor(dh, off));
            const float* lr = logits + (size_t)b * LD;
            float m1 = -3.4e38f, m2 = -3.4e38f;
            for (int j = lane; j < LD; j += 64) {
                float v = lr[j];
                if (v > m1) { m2 = m1; m1 = v; }
                else m2 = fmaxf(m2, v);
            }
#pragma unroll
            for (int off = 1; off < 64; off <<= 1) {
                float o1 = __shfl_xor(m1, off);
                float o2 = __shfl_xor(m2, off);
                if (o1 > m1) { m2 = fmaxf(m1, o2); m1 = o1; }
                else m2 = fmaxf(m2, o1);
            }
            const bool newly = (m1 - m2) > gamma2 * dh;
            if (newly) {
                for (int j = lane; j < LD; j += 64) out[(size_t)b * LD + j] = lr[j];
                if (lane == 0) active[b] = 0;
            } else if (lane == 0) {
                atomicAdd(&nact[t], 1);
            }
        }
        grid.sync();
        const int remaining = ((volatile const int*)nact)[t];
        float* tmp = Hs; Hs = Hn; Hn = tmp;
        if (remaining == 0) break;
    }

    // ---- rows never certified take last-step logits ----
    {
        const int lane = tid & 63;
        const int wave = (bid * 256 + tid) >> 6;
        const int nwaves = nb * 4;
        for (int b = wave; b < BN; b += nwaves) {
            if (!((volatile const int*)active)[b]) continue;
            const float* lr = logits + (size_t)b * LD;
            for (int j = lane; j < LD; j += 64) out[(size_t)b * LD + j] = lr[j];
        }
    }
}

// ---------------------------------------------------------------------------
extern "C" void kernel_launch(void* const* d_in, const int* in_sizes, int n_in,
                              void* d_out, int out_size, void* d_ws, size_t ws_size,
                              hipStream_t stream)
{
    const float* x   = (const float*)d_in[0];
    const float* RIH = (const float*)d_in[1];
    const float* RH  = (const float*)d_in[2];
    const float* RHL = (const float*)d_in[3];
    const float* BH  = (const float*)d_in[4];
    const float* BL  = (const float*)d_in[5];
    const float* MIH = (const float*)d_in[6];
    const float* MH  = (const float*)d_in[7];
    const float* MHL = (const float*)d_in[8];
    float* out = (float*)d_out;
    float* ws  = (float*)d_ws;

    float* W_H    = ws;                                   // 2048*2048
    float* W_HL   = W_H    + (size_t)HDm * HDm;           // 2048*1000
    float* drive  = W_HL   + (size_t)HDm * LD;            // 512*2048
    float* Ha     = drive  + (size_t)BN * HDm;            // 512*2048
    float* Hb     = Ha     + (size_t)BN * HDm;            // 512*2048
    float* logits = Hb     + (size_t)BN * HDm;            // 512*1000
    float* scal   = logits + (size_t)BN * LD;             // 8
    int*   active = (int*)(scal + 8);                     // 512
    int*   nact   = active + BN;                          // 33

    hipMemsetAsync(Ha, 0, (size_t)BN * HDm * sizeof(float), stream);
    k_init<<<2, 256, 0, stream>>>(active, nact, scal);
    k_colsum_wh<<<HDm / 64, 256, 0, stream>>>(RH, MH, scal);
    k_colsum_whl<<<1024 / 64, 256, 0, stream>>>(RHL, MHL, W_HL, scal);
    k_scalars<<<1, 64, 0, stream>>>(scal);
    k_wh<<<(HDm * HDm / 4 + 255) / 256, 256, 0, stream>>>(RH, MH, scal, W_H);
    k_drive<<<256, 256, 0, stream>>>(x, RIH, MIH, BH, drive);

    void* args[] = {(void*)&W_H, (void*)&W_HL, (void*)&drive, (void*)&BL,
                    (void*)&Ha, (void*)&Hb, (void*)&logits,
                    (void*)&active, (void*)&nact, (void*)&scal, (void*)&out};
    hipLaunchCooperativeKernel(reinterpret_cast<void*>(k_crp_loop),
                               dim3(256), dim3(256), args, 0, stream);
}